// Round 1
// baseline (327.657 us; speedup 1.0000x reference)
//
#include <hip/hip_runtime.h>
#include <stdint.h>

// ---------------------------------------------------------------------------
// LocalSelfAttention: B=2 S=8192 HID=1024 NH=16 DH=64 CL=128 NB=1 NA=0
// Pipeline: fp32->bf16 convert, QKV projection GEMMs (bf16 MFMA, fp32 accum),
// chunked local attention with causal mask.
// ---------------------------------------------------------------------------

typedef unsigned short u16;
typedef __bf16 bf16x8 __attribute__((ext_vector_type(8)));
typedef float f32x4 __attribute__((ext_vector_type(4)));

typedef __attribute__((address_space(1))) void* gas_ptr;
typedef __attribute__((address_space(3))) void* las_ptr;

__device__ __forceinline__ u16 f2bf(float f) {
  uint32_t u = __float_as_uint(f);
  u += 0x7fffu + ((u >> 16) & 1u);   // RNE
  return (u16)(u >> 16);
}

__device__ __forceinline__ void gload16(const void* g, void* l) {
  __builtin_amdgcn_global_load_lds((gas_ptr)g, (las_ptr)l, 16, 0, 0);
}

// ---------------- conversion kernels ----------------
__global__ void k_conv_x(const float* __restrict__ x, u16* __restrict__ o, int n4) {
  int i = blockIdx.x * blockDim.x + threadIdx.x;
  int stride = gridDim.x * blockDim.x;
  for (; i < n4; i += stride) {
    float4 v = reinterpret_cast<const float4*>(x)[i];
    unsigned long long pk = (unsigned long long)f2bf(v.x) |
                            ((unsigned long long)f2bf(v.y) << 16) |
                            ((unsigned long long)f2bf(v.z) << 32) |
                            ((unsigned long long)f2bf(v.w) << 48);
    reinterpret_cast<unsigned long long*>(o)[i] = pk;
  }
}

// transpose W [1024 k][1024 n] -> Wt [n][k] bf16; z==1 (Wk) scaled by 0.125
__global__ void k_conv_w(const float* __restrict__ wq, const float* __restrict__ wk,
                         const float* __restrict__ wv, u16* __restrict__ wt) {
  __shared__ float tile[32][33];
  int z = blockIdx.z;
  const float* src = (z == 0) ? wq : (z == 1) ? wk : wv;
  float scale = (z == 1) ? 0.125f : 1.0f;
  int n0 = blockIdx.x * 32, k0 = blockIdx.y * 32;
  int tx = threadIdx.x, ty = threadIdx.y;
  for (int i = ty; i < 32; i += 8)
    tile[i][tx] = src[(size_t)(k0 + i) * 1024 + n0 + tx];
  __syncthreads();
  u16* dst = wt + (size_t)z * 1024 * 1024;
  for (int i = ty; i < 32; i += 8)
    dst[(size_t)(n0 + i) * 1024 + k0 + tx] = f2bf(tile[tx][i] * scale);
}

// ---------------- projection GEMM ----------------
// C[16384 m][1024 n] = Xb[m][k] * Wt[n][k]^T, K=1024, tile 128x128, BK=64.
// TR_OUT=0: q/k -> out[m][1024] bf16 (swapped mfma -> packed stores along n)
// TR_OUT=1: v  -> out[(b*16+h)*64+d][8192 s] bf16 (packed stores along s)
template <int TR_OUT>
__global__ __launch_bounds__(256, 2) void k_gemm(const u16* __restrict__ xb,
                                                 const u16* __restrict__ wt,
                                                 u16* __restrict__ out) {
  __shared__ __align__(16) char lds[32768];
  char* a_s = lds;           // [128][64] bf16, 128B rows, swizzled
  char* b_s = lds + 16384;   // [128][64] bf16
  const int tid = threadIdx.x;
  const int lane = tid & 63, l16 = lane & 15, lhi = lane >> 4;
  const int wave = tid >> 6;
  const int wm = (wave >> 1) * 64, wn = (wave & 1) * 64;
  const int m0 = blockIdx.y * 128, n0 = blockIdx.x * 128;
  const int dstb = (tid & 192) * 16;  // wave*1024

  f32x4 acc[4][4] = {};

  for (int kt = 0; kt < 16; ++kt) {
    __syncthreads();
#pragma unroll
    for (int it = 0; it < 4; ++it) {
      int idx = it * 256 + tid;
      int row = idx >> 3;
      int colb = (idx & 7) * 16;
      int scol = colb ^ ((row & 7) << 4);   // pre-swizzled global source
      gload16((const char*)xb + ((size_t)(m0 + row) * 1024 + kt * 64) * 2 + scol,
              a_s + it * 4096 + dstb);
      gload16((const char*)wt + ((size_t)(n0 + row) * 1024 + kt * 64) * 2 + scol,
              b_s + it * 4096 + dstb);
    }
    __syncthreads();
#pragma unroll
    for (int ks = 0; ks < 2; ++ks) {
      bf16x8 af[4], bf[4];
#pragma unroll
      for (int rb = 0; rb < 4; ++rb) {
        int row = wm + rb * 16 + l16;
        af[rb] = *(const bf16x8*)(a_s + row * 128 + ((ks * 64 + lhi * 16) ^ ((row & 7) << 4)));
      }
#pragma unroll
      for (int nb = 0; nb < 4; ++nb) {
        int row = wn + nb * 16 + l16;
        bf[nb] = *(const bf16x8*)(b_s + row * 128 + ((ks * 64 + lhi * 16) ^ ((row & 7) << 4)));
      }
#pragma unroll
      for (int rb = 0; rb < 4; ++rb) {
#pragma unroll
        for (int nb = 0; nb < 4; ++nb) {
          if constexpr (TR_OUT)
            acc[rb][nb] = __builtin_amdgcn_mfma_f32_16x16x32_bf16(af[rb], bf[nb], acc[rb][nb], 0, 0, 0);
          else  // swapped: acc holds C^T fragment (rows=n, cols=m)
            acc[rb][nb] = __builtin_amdgcn_mfma_f32_16x16x32_bf16(bf[nb], af[rb], acc[rb][nb], 0, 0, 0);
        }
      }
    }
  }

  if constexpr (!TR_OUT) {
    // C^T frag: lane holds 4 consecutive n for fixed m -> one 8B store
#pragma unroll
    for (int rb = 0; rb < 4; ++rb) {
#pragma unroll
      for (int nb = 0; nb < 4; ++nb) {
        int m = m0 + wm + rb * 16 + l16;
        int n = n0 + wn + nb * 16 + lhi * 4;
        unsigned long long pk = (unsigned long long)f2bf(acc[rb][nb][0]) |
                                ((unsigned long long)f2bf(acc[rb][nb][1]) << 16) |
                                ((unsigned long long)f2bf(acc[rb][nb][2]) << 32) |
                                ((unsigned long long)f2bf(acc[rb][nb][3]) << 48);
        *(unsigned long long*)((char*)out + ((size_t)m * 1024 + n) * 2) = pk;
      }
    }
  } else {
    // normal C: lane holds 4 consecutive m(=s) for fixed n -> 8B store into v_t[n + b*1024][s]
#pragma unroll
    for (int rb = 0; rb < 4; ++rb) {
#pragma unroll
      for (int nb = 0; nb < 4; ++nb) {
        int m = m0 + wm + rb * 16 + lhi * 4;   // s base, +j
        int n = n0 + wn + nb * 16 + l16;       // h*64+d
        int bb = m >> 13;
        int s = m & 8191;
        unsigned long long pk = (unsigned long long)f2bf(acc[rb][nb][0]) |
                                ((unsigned long long)f2bf(acc[rb][nb][1]) << 16) |
                                ((unsigned long long)f2bf(acc[rb][nb][2]) << 32) |
                                ((unsigned long long)f2bf(acc[rb][nb][3]) << 48);
        *(unsigned long long*)((char*)out + ((size_t)(bb * 1024 + n) * 8192 + s) * 2) = pk;
      }
    }
  }
}

// ---------------- attention ----------------
// grid = B*NH*NC = 2048 blocks, 256 threads (4 waves), wave owns 32 q-rows.
__global__ __launch_bounds__(256, 2) void k_attn(const u16* __restrict__ qw,
                                                 const u16* __restrict__ kw,
                                                 const u16* __restrict__ vt,
                                                 float* __restrict__ out) {
  __shared__ __align__(16) char lds[81920];
  char* q_s = lds;           // [128][64] bf16 16KB (swz)
  char* k_s = lds + 16384;   // [256][64] bf16 32KB (swz)
  char* v_s = lds + 49152;   // [64 d][256 key] bf16 32KB (swz, 512B rows)
  const int tid = threadIdx.x;
  const int lane = tid & 63, l16 = lane & 15, lhi = lane >> 4;
  const int wave = tid >> 6;
  char* p_s = lds + wave * 8192;  // [32][128] bf16 per wave, reuses q_s/k_s after S-phase
  const int c = blockIdx.x & 63;
  const int h = (blockIdx.x >> 6) & 15;
  const int b = blockIdx.x >> 10;
  const int cprev = (c == 0) ? 0 : c - 1;   // chunk0 prev is fully masked; load own data
  const int dstb = (tid & 192) * 16;

  // ---- stage q/k/v via global_load_lds (pre-swizzled sources)
#pragma unroll
  for (int it = 0; it < 4; ++it) {
    int idx = it * 256 + tid;
    int row = idx >> 3, colb = (idx & 7) * 16;
    gload16((const char*)qw + ((size_t)(b * 8192 + c * 128 + row) * 1024 + h * 64) * 2 +
                (colb ^ ((row & 7) << 4)),
            q_s + it * 4096 + dstb);
  }
#pragma unroll
  for (int it = 0; it < 8; ++it) {
    int idx = it * 256 + tid;
    int row = idx >> 3, colb = (idx & 7) * 16;
    int srow = (row < 128) ? (cprev * 128 + row) : (c * 128 + row - 128);
    gload16((const char*)kw + ((size_t)(b * 8192 + srow) * 1024 + h * 64) * 2 +
                (colb ^ ((row & 7) << 4)),
            k_s + it * 4096 + dstb);
  }
#pragma unroll
  for (int it = 0; it < 8; ++it) {
    int idx = it * 256 + tid;
    int row = idx >> 5;                   // d
    int colb = (idx & 31) * 16;           // dest byte in 512B row
    int colbl = colb ^ ((row & 7) << 4);  // logical key-byte*2
    size_t roff = ((size_t)((b * 16 + h) * 64 + row)) * 8192 * 2;
    size_t soff = c ? ((size_t)(c * 128 - 128) * 2 + colbl) : (size_t)(colbl & 255);
    gload16((const char*)vt + roff + soff, v_s + it * 4096 + dstb);
  }
  __syncthreads();

  // ---- S = q @ k^T  (per-wave rows rbase..rbase+31, all 256 keys)
  const int rbase = wave * 32;
  f32x4 accs[2][16];
#pragma unroll
  for (int rb = 0; rb < 2; ++rb)
#pragma unroll
    for (int nb = 0; nb < 16; ++nb) accs[rb][nb] = f32x4{0.f, 0.f, 0.f, 0.f};

#pragma unroll
  for (int ks = 0; ks < 2; ++ks) {
    bf16x8 af[2];
#pragma unroll
    for (int rb = 0; rb < 2; ++rb) {
      int row = rbase + rb * 16 + l16;
      af[rb] = *(const bf16x8*)(q_s + row * 128 + ((ks * 64 + lhi * 16) ^ ((row & 7) << 4)));
    }
#pragma unroll
    for (int nb = 0; nb < 16; ++nb) {
      int row = nb * 16 + l16;
      bf16x8 bfb = *(const bf16x8*)(k_s + row * 128 + ((ks * 64 + lhi * 16) ^ ((row & 7) << 4)));
#pragma unroll
      for (int rb = 0; rb < 2; ++rb)
        accs[rb][nb] = __builtin_amdgcn_mfma_f32_16x16x32_bf16(af[rb], bfb, accs[rb][nb], 0, 0, 0);
    }
  }

  // ---- causal mask + wave-local softmax (rows map: r = rb*16 + lhi*4 + j)
  float rinv[2][4];
#pragma unroll
  for (int rb = 0; rb < 2; ++rb) {
#pragma unroll
    for (int j = 0; j < 4; ++j) {
      int qi = rbase + rb * 16 + lhi * 4 + j;   // 0..127 in chunk
      float m = -3.0e38f;
#pragma unroll
      for (int nb = 0; nb < 16; ++nb) {
        int kl = nb * 16 + l16;                 // 0..255 (0..127 = prev chunk)
        float v = accs[rb][nb][j];
        bool valid = (kl <= qi + 128) && ((c > 0) || (kl >= 128));
        v = valid ? v : -1.0e9f;
        accs[rb][nb][j] = v;
        m = fmaxf(m, v);
      }
#pragma unroll
      for (int d = 1; d < 16; d <<= 1) m = fmaxf(m, __shfl_xor(m, d));
      float s = 0.f;
#pragma unroll
      for (int nb = 0; nb < 16; ++nb) {
        float e = __expf(accs[rb][nb][j] - m);
        accs[rb][nb][j] = e;
        s += e;
      }
#pragma unroll
      for (int d = 1; d < 16; d <<= 1) s += __shfl_xor(s, d);
      rinv[rb][j] = 1.0f / s;
    }
  }

  __syncthreads();   // everyone done reading q_s/k_s before P overwrites them

  // ---- PV in two 128-key halves (P per-wave in LDS)
  f32x4 acco[2][4] = {};
#pragma unroll
  for (int half = 0; half < 2; ++half) {
#pragma unroll
    for (int rb = 0; rb < 2; ++rb) {
#pragma unroll
      for (int nbh = 0; nbh < 8; ++nbh) {
#pragma unroll
        for (int j = 0; j < 4; ++j) {
          int r = rb * 16 + lhi * 4 + j;
          int cb = (nbh * 16 + l16) * 2;
          *(u16*)(p_s + r * 256 + (cb ^ ((r & 7) << 4))) = f2bf(accs[rb][half * 8 + nbh][j]);
        }
      }
    }
    __asm__ volatile("s_waitcnt lgkmcnt(0)" ::: "memory");
    __builtin_amdgcn_sched_barrier(0);
#pragma unroll
    for (int ks = 0; ks < 4; ++ks) {
      bf16x8 pf[2];
#pragma unroll
      for (int rb = 0; rb < 2; ++rb) {
        int r = rb * 16 + l16;
        pf[rb] = *(const bf16x8*)(p_s + r * 256 + ((ks * 64 + lhi * 16) ^ ((r & 7) << 4)));
      }
#pragma unroll
      for (int db = 0; db < 4; ++db) {
        int vr = db * 16 + l16;
        bf16x8 vf = *(const bf16x8*)(v_s + vr * 512 +
                                     ((half * 256 + ks * 64 + lhi * 16) ^ ((vr & 7) << 4)));
#pragma unroll
        for (int rb = 0; rb < 2; ++rb)
          acco[rb][db] = __builtin_amdgcn_mfma_f32_16x16x32_bf16(pf[rb], vf, acco[rb][db], 0, 0, 0);
      }
    }
    if (half == 0) {
      __asm__ volatile("s_waitcnt lgkmcnt(0)" ::: "memory");
      __builtin_amdgcn_sched_barrier(0);
    }
  }

  // ---- epilogue: out[b][s][h*64 + d], scaled by 1/rowsum
#pragma unroll
  for (int rb = 0; rb < 2; ++rb) {
#pragma unroll
    for (int db = 0; db < 4; ++db) {
#pragma unroll
      for (int j = 0; j < 4; ++j) {
        int r = rbase + rb * 16 + lhi * 4 + j;
        out[(size_t)(b * 8192 + c * 128 + r) * 1024 + h * 64 + db * 16 + l16] =
            acco[rb][db][j] * rinv[rb][j];
      }
    }
  }
}

// ---------------- launcher ----------------
extern "C" void kernel_launch(void* const* d_in, const int* in_sizes, int n_in,
                              void* d_out, int out_size, void* d_ws, size_t ws_size,
                              hipStream_t stream) {
  const float* hs = (const float*)d_in[0];
  const float* wq = (const float*)d_in[1];
  const float* wk = (const float*)d_in[2];
  const float* wv = (const float*)d_in[3];
  float* out = (float*)d_out;
  char* ws = (char*)d_ws;

  u16* x_bf = (u16*)ws;                          // 16384*1024 bf16   (33,554,432 B)
  u16* wt   = (u16*)(ws + 33554432);             // 3*1024*1024 bf16  ( 6,291,456 B)
  u16* q_ws = (u16*)(ws + 39845888);             // [16384][1024] bf16
  u16* k_ws = (u16*)(ws + 73400320);             // [16384][1024] bf16 (pre-scaled 1/8)
  u16* v_t  = (u16*)(ws + 106954752);            // [2*1024][8192] bf16 (transposed)

  k_conv_x<<<dim3(2048), dim3(256), 0, stream>>>(hs, x_bf, 16384 * 1024 / 4);
  k_conv_w<<<dim3(32, 32, 3), dim3(32, 8), 0, stream>>>(wq, wk, wv, wt);
  k_gemm<0><<<dim3(8, 128), dim3(256), 0, stream>>>(x_bf, wt, q_ws);
  k_gemm<0><<<dim3(8, 128), dim3(256), 0, stream>>>(x_bf, wt + 1024 * 1024, k_ws);
  k_gemm<1><<<dim3(8, 128), dim3(256), 0, stream>>>(x_bf, wt + 2 * 1024 * 1024, v_t);
  k_attn<<<dim3(2048), dim3(256), 0, stream>>>(q_ws, k_ws, v_t, out);
}

// Round 3
// 297.006 us; speedup vs baseline: 1.1032x; 1.1032x over previous
//
#include <hip/hip_runtime.h>
#include <stdint.h>

// ---------------------------------------------------------------------------
// LocalSelfAttention: B=2 S=8192 HID=1024 NH=16 DH=64 CL=128 NB=1 NA=0
// Round 2 (resubmit): QKV projection GEMMs on 256x256 8-phase deep-pipelined
// schedule (T2 swizzle + T3/T4 counted vmcnt + T5 setprio). Attn unchanged.
// ---------------------------------------------------------------------------

typedef unsigned short u16;
typedef __bf16 bf16x8 __attribute__((ext_vector_type(8)));
typedef float f32x4 __attribute__((ext_vector_type(4)));

typedef __attribute__((address_space(1))) void* gas_ptr;
typedef __attribute__((address_space(3))) void* las_ptr;

__device__ __forceinline__ u16 f2bf(float f) {
  uint32_t u = __float_as_uint(f);
  u += 0x7fffu + ((u >> 16) & 1u);   // RNE
  return (u16)(u >> 16);
}

__device__ __forceinline__ void gload16(const void* g, void* l) {
  __builtin_amdgcn_global_load_lds((gas_ptr)g, (las_ptr)l, 16, 0, 0);
}

// ---------------- conversion kernels ----------------
__global__ void k_conv_x(const float* __restrict__ x, u16* __restrict__ o, int n4) {
  int i = blockIdx.x * blockDim.x + threadIdx.x;
  int stride = gridDim.x * blockDim.x;
  for (; i < n4; i += stride) {
    float4 v = reinterpret_cast<const float4*>(x)[i];
    unsigned long long pk = (unsigned long long)f2bf(v.x) |
                            ((unsigned long long)f2bf(v.y) << 16) |
                            ((unsigned long long)f2bf(v.z) << 32) |
                            ((unsigned long long)f2bf(v.w) << 48);
    reinterpret_cast<unsigned long long*>(o)[i] = pk;
  }
}

// transpose W [1024 k][1024 n] -> Wt [n][k] bf16; z==1 (Wk) scaled by 0.125
__global__ void k_conv_w(const float* __restrict__ wq, const float* __restrict__ wk,
                         const float* __restrict__ wv, u16* __restrict__ wt) {
  __shared__ float tile[32][33];
  int z = blockIdx.z;
  const float* src = (z == 0) ? wq : (z == 1) ? wk : wv;
  float scale = (z == 1) ? 0.125f : 1.0f;
  int n0 = blockIdx.x * 32, k0 = blockIdx.y * 32;
  int tx = threadIdx.x, ty = threadIdx.y;
  for (int i = ty; i < 32; i += 8)
    tile[i][tx] = src[(size_t)(k0 + i) * 1024 + n0 + tx];
  __syncthreads();
  u16* dst = wt + (size_t)z * 1024 * 1024;
  for (int i = ty; i < 32; i += 8)
    dst[(size_t)(n0 + i) * 1024 + k0 + tx] = f2bf(tile[tx][i] * scale);
}

// ---------------- projection GEMM: 256x256 tile, BK=64, 8 waves, 8-phase ----
// C[16384 m][1024 n] = Xb[m][k] * Wt[n][k]^T, K=1024 (16 K-tiles).
// LDS: A,B each [2 dbuf][256 rows][64 bf16] (swizzled 128B rows) = 128 KiB.
// A-half h = rows with bit6==h; B-half h = rows with bit5==h. Phase p
// (quadrant mh=p&1, nh=p>>1) reads exactly halves A(mh), B(nh).
// Stage order per K-tile t (into buf (t+1)&1, for tile t+1): p0:A0 p1:B0
// p2:A1 p3:B1 -> uniform vmcnt(4) at p0,p1,p2 drains exactly what's needed.
template <int TR_OUT>
__global__ __launch_bounds__(512, 2) void k_gemm(const u16* __restrict__ xb,
                                                 const u16* __restrict__ wt,
                                                 u16* __restrict__ out) {
  __shared__ __align__(16) char lds[131072];
  char* As = lds;            // [2][256][64] bf16
  char* Bs = lds + 65536;
  const int tid = threadIdx.x;
  const int lane = tid & 63, l16 = lane & 15, lhi = lane >> 4;
  const int wave = tid >> 6;
  const int wm = (wave >> 2) * 128;   // WARPS_M=2
  const int wn = (wave & 3) * 64;     // WARPS_N=4
  // XCD-bijective remap: 256 blocks -> 32 consecutive work items per XCD
  const int bid = blockIdx.x;
  const int wg = (bid & 7) * 32 + (bid >> 3);
  const int m0 = (wg >> 2) * 256;
  const int n0 = (wg & 3) * 256;

  const int lrow8 = lane >> 3;                          // 0..7
  const int scolx = ((lane & 7) * 16) ^ (lrow8 << 4);   // pre-swizzled col byte

  f32x4 acc[8][4] = {};

  auto stA = [&](int buf, int kt, int h) {
#pragma unroll
    for (int i = 0; i < 2; ++i) {
      int j = wave * 2 + i;
      int rb = 8 * j + 64 * (h + (j >> 3));   // 8-row group base, bit6==h
      int row = rb + lrow8;
      gload16((const char*)xb + ((size_t)(m0 + row) * 1024 + kt * 64) * 2 + scolx,
              As + buf * 32768 + rb * 128);
    }
  };
  auto stB = [&](int buf, int kt, int h) {
#pragma unroll
    for (int i = 0; i < 2; ++i) {
      int j = wave * 2 + i;
      int rb = 8 * (j & 3) + (j >> 2) * 64 + h * 32;   // bit5==h
      int row = rb + lrow8;
      gload16((const char*)wt + ((size_t)(n0 + row) * 1024 + kt * 64) * 2 + scolx,
              Bs + buf * 32768 + rb * 128);
    }
  };

  // prologue: tile 0 -> buf0 (order A0,B0,A1,B1; 8 loads/thread in flight)
  stA(0, 0, 0); stB(0, 0, 0); stA(0, 0, 1); stB(0, 0, 1);

  for (int t = 0; t < 16; ++t) {
    const int cbuf = t & 1, nbuf = cbuf ^ 1;
    const int ktn = (t < 15) ? t + 1 : 15;   // wrap: harmless re-stage
#pragma unroll
    for (int p = 0; p < 4; ++p) {
      __builtin_amdgcn_sched_barrier(0);
      if (p < 3) asm volatile("s_waitcnt vmcnt(4)" ::: "memory");
      __builtin_amdgcn_s_barrier();
      __builtin_amdgcn_sched_barrier(0);
      const int mh = p & 1, nh = p >> 1;
      bf16x8 af[4][2], bfr[2][2];
#pragma unroll
      for (int fi = 0; fi < 4; ++fi) {
        int row = wm + (mh * 4 + fi) * 16 + l16;
#pragma unroll
        for (int ks = 0; ks < 2; ++ks)
          af[fi][ks] = *(const bf16x8*)(As + cbuf * 32768 + row * 128 +
                                        ((ks * 64 + lhi * 16) ^ ((row & 7) << 4)));
      }
#pragma unroll
      for (int f2 = 0; f2 < 2; ++f2) {
        int rn = wn + nh * 32 + f2 * 16 + l16;
#pragma unroll
        for (int ks = 0; ks < 2; ++ks)
          bfr[f2][ks] = *(const bf16x8*)(Bs + cbuf * 32768 + rn * 128 +
                                         ((ks * 64 + lhi * 16) ^ ((rn & 7) << 4)));
      }
      // stage one half-tile of tile t+1
      if (p == 0) stA(nbuf, ktn, 0);
      else if (p == 1) stB(nbuf, ktn, 0);
      else if (p == 2) stA(nbuf, ktn, 1);
      else stB(nbuf, ktn, 1);
      asm volatile("s_waitcnt lgkmcnt(0)" ::: "memory");
      __builtin_amdgcn_sched_barrier(0);
      __builtin_amdgcn_s_setprio(1);
#pragma unroll
      for (int fi = 0; fi < 4; ++fi)
#pragma unroll
        for (int f2 = 0; f2 < 2; ++f2)
#pragma unroll
          for (int ks = 0; ks < 2; ++ks) {
            if constexpr (TR_OUT)
              acc[mh * 4 + fi][nh * 2 + f2] = __builtin_amdgcn_mfma_f32_16x16x32_bf16(
                  af[fi][ks], bfr[f2][ks], acc[mh * 4 + fi][nh * 2 + f2], 0, 0, 0);
            else  // swapped: acc holds C^T fragment (rows=n, cols=m)
              acc[mh * 4 + fi][nh * 2 + f2] = __builtin_amdgcn_mfma_f32_16x16x32_bf16(
                  bfr[f2][ks], af[fi][ks], acc[mh * 4 + fi][nh * 2 + f2], 0, 0, 0);
          }
      __builtin_amdgcn_s_setprio(0);
    }
  }

  if constexpr (!TR_OUT) {
    // C^T frag: lane holds 4 consecutive n for fixed m -> one 8B store
#pragma unroll
    for (int fr = 0; fr < 8; ++fr) {
#pragma unroll
      for (int fn = 0; fn < 4; ++fn) {
        int m = m0 + wm + fr * 16 + l16;
        int n = n0 + wn + fn * 16 + lhi * 4;
        unsigned long long pk = (unsigned long long)f2bf(acc[fr][fn][0]) |
                                ((unsigned long long)f2bf(acc[fr][fn][1]) << 16) |
                                ((unsigned long long)f2bf(acc[fr][fn][2]) << 32) |
                                ((unsigned long long)f2bf(acc[fr][fn][3]) << 48);
        *(unsigned long long*)((char*)out + ((size_t)m * 1024 + n) * 2) = pk;
      }
    }
  } else {
    // normal C: lane holds 4 consecutive m(=s) -> 8B store into v_t[b*1024+n][s]
#pragma unroll
    for (int fr = 0; fr < 8; ++fr) {
#pragma unroll
      for (int fn = 0; fn < 4; ++fn) {
        int m = m0 + wm + fr * 16 + lhi * 4;
        int n = n0 + wn + fn * 16 + l16;
        int bb = m >> 13;
        int s = m & 8191;
        unsigned long long pk = (unsigned long long)f2bf(acc[fr][fn][0]) |
                                ((unsigned long long)f2bf(acc[fr][fn][1]) << 16) |
                                ((unsigned long long)f2bf(acc[fr][fn][2]) << 32) |
                                ((unsigned long long)f2bf(acc[fr][fn][3]) << 48);
        *(unsigned long long*)((char*)out + ((size_t)(bb * 1024 + n) * 8192 + s) * 2) = pk;
      }
    }
  }
}

// ---------------- attention ----------------
// grid = B*NH*NC = 2048 blocks, 256 threads (4 waves), wave owns 32 q-rows.
__global__ __launch_bounds__(256, 2) void k_attn(const u16* __restrict__ qw,
                                                 const u16* __restrict__ kw,
                                                 const u16* __restrict__ vt,
                                                 float* __restrict__ out) {
  __shared__ __align__(16) char lds[81920];
  char* q_s = lds;           // [128][64] bf16 16KB (swz)
  char* k_s = lds + 16384;   // [256][64] bf16 32KB (swz)
  char* v_s = lds + 49152;   // [64 d][256 key] bf16 32KB (swz, 512B rows)
  const int tid = threadIdx.x;
  const int lane = tid & 63, l16 = lane & 15, lhi = lane >> 4;
  const int wave = tid >> 6;
  char* p_s = lds + wave * 8192;  // [32][128] bf16 per wave, reuses q_s/k_s after S-phase
  const int c = blockIdx.x & 63;
  const int h = (blockIdx.x >> 6) & 15;
  const int b = blockIdx.x >> 10;
  const int cprev = (c == 0) ? 0 : c - 1;   // chunk0 prev is fully masked; load own data
  const int dstb = (tid & 192) * 16;

  // ---- stage q/k/v via global_load_lds (pre-swizzled sources)
#pragma unroll
  for (int it = 0; it < 4; ++it) {
    int idx = it * 256 + tid;
    int row = idx >> 3, colb = (idx & 7) * 16;
    gload16((const char*)qw + ((size_t)(b * 8192 + c * 128 + row) * 1024 + h * 64) * 2 +
                (colb ^ ((row & 7) << 4)),
            q_s + it * 4096 + dstb);
  }
#pragma unroll
  for (int it = 0; it < 8; ++it) {
    int idx = it * 256 + tid;
    int row = idx >> 3, colb = (idx & 7) * 16;
    int srow = (row < 128) ? (cprev * 128 + row) : (c * 128 + row - 128);
    gload16((const char*)kw + ((size_t)(b * 8192 + srow) * 1024 + h * 64) * 2 +
                (colb ^ ((row & 7) << 4)),
            k_s + it * 4096 + dstb);
  }
#pragma unroll
  for (int it = 0; it < 8; ++it) {
    int idx = it * 256 + tid;
    int row = idx >> 5;                   // d
    int colb = (idx & 31) * 16;           // dest byte in 512B row
    int colbl = colb ^ ((row & 7) << 4);  // logical key-byte*2
    size_t roff = ((size_t)((b * 16 + h) * 64 + row)) * 8192 * 2;
    size_t soff = c ? ((size_t)(c * 128 - 128) * 2 + colbl) : (size_t)(colbl & 255);
    gload16((const char*)vt + roff + soff, v_s + it * 4096 + dstb);
  }
  __syncthreads();

  // ---- S = q @ k^T  (per-wave rows rbase..rbase+31, all 256 keys)
  const int rbase = wave * 32;
  f32x4 accs[2][16];
#pragma unroll
  for (int rb = 0; rb < 2; ++rb)
#pragma unroll
    for (int nb = 0; nb < 16; ++nb) accs[rb][nb] = f32x4{0.f, 0.f, 0.f, 0.f};

#pragma unroll
  for (int ks = 0; ks < 2; ++ks) {
    bf16x8 af[2];
#pragma unroll
    for (int rb = 0; rb < 2; ++rb) {
      int row = rbase + rb * 16 + l16;
      af[rb] = *(const bf16x8*)(q_s + row * 128 + ((ks * 64 + lhi * 16) ^ ((row & 7) << 4)));
    }
#pragma unroll
    for (int nb = 0; nb < 16; ++nb) {
      int row = nb * 16 + l16;
      bf16x8 bfb = *(const bf16x8*)(k_s + row * 128 + ((ks * 64 + lhi * 16) ^ ((row & 7) << 4)));
#pragma unroll
      for (int rb = 0; rb < 2; ++rb)
        accs[rb][nb] = __builtin_amdgcn_mfma_f32_16x16x32_bf16(af[rb], bfb, accs[rb][nb], 0, 0, 0);
    }
  }

  // ---- causal mask + wave-local softmax (rows map: r = rb*16 + lhi*4 + j)
  float rinv[2][4];
#pragma unroll
  for (int rb = 0; rb < 2; ++rb) {
#pragma unroll
    for (int j = 0; j < 4; ++j) {
      int qi = rbase + rb * 16 + lhi * 4 + j;   // 0..127 in chunk
      float m = -3.0e38f;
#pragma unroll
      for (int nb = 0; nb < 16; ++nb) {
        int kl = nb * 16 + l16;                 // 0..255 (0..127 = prev chunk)
        float v = accs[rb][nb][j];
        bool valid = (kl <= qi + 128) && ((c > 0) || (kl >= 128));
        v = valid ? v : -1.0e9f;
        accs[rb][nb][j] = v;
        m = fmaxf(m, v);
      }
#pragma unroll
      for (int d = 1; d < 16; d <<= 1) m = fmaxf(m, __shfl_xor(m, d));
      float s = 0.f;
#pragma unroll
      for (int nb = 0; nb < 16; ++nb) {
        float e = __expf(accs[rb][nb][j] - m);
        accs[rb][nb][j] = e;
        s += e;
      }
#pragma unroll
      for (int d = 1; d < 16; d <<= 1) s += __shfl_xor(s, d);
      rinv[rb][j] = 1.0f / s;
    }
  }

  __syncthreads();   // everyone done reading q_s/k_s before P overwrites them

  // ---- PV in two 128-key halves (P per-wave in LDS)
  f32x4 acco[2][4] = {};
#pragma unroll
  for (int half = 0; half < 2; ++half) {
#pragma unroll
    for (int rb = 0; rb < 2; ++rb) {
#pragma unroll
      for (int nbh = 0; nbh < 8; ++nbh) {
#pragma unroll
        for (int j = 0; j < 4; ++j) {
          int r = rb * 16 + lhi * 4 + j;
          int cb = (nbh * 16 + l16) * 2;
          *(u16*)(p_s + r * 256 + (cb ^ ((r & 7) << 4))) = f2bf(accs[rb][half * 8 + nbh][j]);
        }
      }
    }
    __asm__ volatile("s_waitcnt lgkmcnt(0)" ::: "memory");
    __builtin_amdgcn_sched_barrier(0);
#pragma unroll
    for (int ks = 0; ks < 4; ++ks) {
      bf16x8 pf[2];
#pragma unroll
      for (int rb = 0; rb < 2; ++rb) {
        int r = rb * 16 + l16;
        pf[rb] = *(const bf16x8*)(p_s + r * 256 + ((ks * 64 + lhi * 16) ^ ((r & 7) << 4)));
      }
#pragma unroll
      for (int db = 0; db < 4; ++db) {
        int vr = db * 16 + l16;
        bf16x8 vf = *(const bf16x8*)(v_s + vr * 512 +
                                     ((half * 256 + ks * 64 + lhi * 16) ^ ((vr & 7) << 4)));
#pragma unroll
        for (int rb = 0; rb < 2; ++rb)
          acco[rb][db] = __builtin_amdgcn_mfma_f32_16x16x32_bf16(pf[rb], vf, acco[rb][db], 0, 0, 0);
      }
    }
    if (half == 0) {
      __asm__ volatile("s_waitcnt lgkmcnt(0)" ::: "memory");
      __builtin_amdgcn_sched_barrier(0);
    }
  }

  // ---- epilogue: out[b][s][h*64 + d], scaled by 1/rowsum
#pragma unroll
  for (int rb = 0; rb < 2; ++rb) {
#pragma unroll
    for (int db = 0; db < 4; ++db) {
#pragma unroll
      for (int j = 0; j < 4; ++j) {
        int r = rbase + rb * 16 + lhi * 4 + j;
        out[(size_t)(b * 8192 + c * 128 + r) * 1024 + h * 64 + db * 16 + l16] =
            acco[rb][db][j] * rinv[rb][j];
      }
    }
  }
}

// ---------------- launcher ----------------
extern "C" void kernel_launch(void* const* d_in, const int* in_sizes, int n_in,
                              void* d_out, int out_size, void* d_ws, size_t ws_size,
                              hipStream_t stream) {
  const float* hs = (const float*)d_in[0];
  const float* wq = (const float*)d_in[1];
  const float* wk = (const float*)d_in[2];
  const float* wv = (const float*)d_in[3];
  float* out = (float*)d_out;
  char* ws = (char*)d_ws;

  u16* x_bf = (u16*)ws;                          // 16384*1024 bf16   (33,554,432 B)
  u16* wt   = (u16*)(ws + 33554432);             // 3*1024*1024 bf16  ( 6,291,456 B)
  u16* q_ws = (u16*)(ws + 39845888);             // [16384][1024] bf16
  u16* k_ws = (u16*)(ws + 73400320);             // [16384][1024] bf16 (pre-scaled 1/8)
  u16* v_t  = (u16*)(ws + 106954752);            // [2*1024][8192] bf16 (transposed)

  k_conv_x<<<dim3(2048), dim3(256), 0, stream>>>(hs, x_bf, 16384 * 1024 / 4);
  k_conv_w<<<dim3(32, 32, 3), dim3(32, 8), 0, stream>>>(wq, wk, wv, wt);
  k_gemm<0><<<dim3(256), dim3(512), 0, stream>>>(x_bf, wt, q_ws);
  k_gemm<0><<<dim3(256), dim3(512), 0, stream>>>(x_bf, wt + 1024 * 1024, k_ws);
  k_gemm<1><<<dim3(256), dim3(512), 0, stream>>>(x_bf, wt + 2 * 1024 * 1024, v_t);
  k_attn<<<dim3(2048), dim3(256), 0, stream>>>(q_ws, k_ws, v_t, out);
}